// Round 2
// baseline (3471.251 us; speedup 1.0000x reference)
//
#include <hip/hip_runtime.h>
#include <hip/hip_bf16.h>
#include <math.h>

#define B_ 8
#define C_ 128
#define H_ 64
#define W_ 64
#define HW_ 4096
#define HEADS_ 8
#define CH_ 16
#define HID_ 512

__device__ __forceinline__ float toF(float v) { return v; }
__device__ __forceinline__ float toF(__hip_bfloat16 v) { return __bfloat162float(v); }
__device__ __forceinline__ void storeF(float* p, float v) { *p = v; }
__device__ __forceinline__ void storeF(__hip_bfloat16* p, float v) { *p = __float2bfloat16(v); }

// ---------------- LayerNorm over channel dim ----------------
__global__ __launch_bounds__(256) void ln_ch(const float* __restrict__ x,
                                             const float* __restrict__ w,
                                             const float* __restrict__ b,
                                             float* __restrict__ out) {
  int p = blockIdx.x * 256 + threadIdx.x;  // over B*HW
  if (p >= B_ * HW_) return;
  int bi = p >> 12;
  int pos = p & (HW_ - 1);
  const float* xb = x + (size_t)bi * C_ * HW_ + pos;
  float s = 0.f, ss = 0.f;
  for (int c = 0; c < C_; c++) {
    float v = xb[(size_t)c * HW_];
    s += v;
    ss = fmaf(v, v, ss);
  }
  float mu = s * (1.f / C_);
  float var = ss * (1.f / C_) - mu * mu;
  float inv = rsqrtf(var + 1e-5f);
  float* ob = out + (size_t)bi * C_ * HW_ + pos;
  for (int c = 0; c < C_; c++) {
    ob[(size_t)c * HW_] = (xb[(size_t)c * HW_] - mu) * inv * w[c] + b[c];
  }
}

// ---------------- generic conv1x1 (GEMM over channels), 8 outputs/block ----------------
template <typename Tin, typename Tout>
__global__ __launch_bounds__(256) void conv1x1_k(const Tin* __restrict__ in,
                                                 const float* __restrict__ wt,
                                                 const float* __restrict__ resid,
                                                 Tout* __restrict__ out,
                                                 int cin, int cout, int wstride,
                                                 int accum) {
  int tid = threadIdx.x;
  int blk = blockIdx.x;
  int pb = blk & 15;  // HW_/256 = 16 position blocks
  int t = blk >> 4;
  int nob = cout >> 3;
  int ob = t % nob;
  int bi = t / nob;
  int pos = (pb << 8) + tid;
  int o0 = ob << 3;
  const Tin* ib = in + (size_t)bi * cin * HW_ + pos;
  float acc[8] = {0.f, 0.f, 0.f, 0.f, 0.f, 0.f, 0.f, 0.f};
  for (int c = 0; c < cin; c++) {
    float xv = toF(ib[(size_t)c * HW_]);
    const float* wr = wt + (size_t)o0 * wstride + c;
#pragma unroll
    for (int j = 0; j < 8; j++) acc[j] = fmaf(wr[(size_t)j * wstride], xv, acc[j]);
  }
  Tout* op = out + ((size_t)bi * cout + o0) * HW_ + pos;
  const float* rp = resid ? resid + ((size_t)bi * cout + o0) * HW_ + pos : nullptr;
#pragma unroll
  for (int j = 0; j < 8; j++) {
    float v = acc[j];
    if (rp) v += rp[(size_t)j * HW_];
    if (accum) v += toF(op[(size_t)j * HW_]);
    storeF(&op[(size_t)j * HW_], v);
  }
}

// ---------------- depthwise conv KxK, same padding (fp32) ----------------
template <int K>
__global__ __launch_bounds__(256) void dwconv_k(const float* __restrict__ in,
                                                const float* __restrict__ w,
                                                float* __restrict__ out) {
  int id = blockIdx.x * 256 + threadIdx.x;  // over B*C*HW
  int pos = id & (HW_ - 1);
  int xx = pos & (W_ - 1);
  int yy = pos >> 6;
  int bc = id >> 12;
  int c = bc & (C_ - 1);
  constexpr int P = K / 2;
  const float* ib = in + (size_t)bc * HW_;
  const float* wr = w + c * K * K;
  float acc = 0.f;
#pragma unroll
  for (int dy = 0; dy < K; dy++) {
    int y2 = yy + dy - P;
    if ((unsigned)y2 >= (unsigned)H_) continue;
#pragma unroll
    for (int dx = 0; dx < K; dx++) {
      int x2 = xx + dx - P;
      if ((unsigned)x2 >= (unsigned)W_) continue;
      acc = fmaf(ib[y2 * W_ + x2], wr[dy * K + dx], acc);
    }
  }
  out[(size_t)id] = acc;
}

// ---------------- inverse L2 norms of qd and kd rows ----------------
__global__ __launch_bounds__(256) void l2_invnorm(const float* __restrict__ qd,
                                                  const float* __restrict__ kd,
                                                  float* __restrict__ invn) {
  int row = blockIdx.x;  // 0..2047; <1024 -> qd, else kd
  const float* src = (row < 1024) ? (qd + (size_t)row * HW_)
                                  : (kd + (size_t)(row - 1024) * HW_);
  float s = 0.f;
  for (int n = threadIdx.x; n < HW_; n += 256) {
    float v = src[n];
    s = fmaf(v, v, s);
  }
#pragma unroll
  for (int o = 32; o >= 1; o >>= 1) s += __shfl_xor(s, o, 64);
  __shared__ float red[4];
  if ((threadIdx.x & 63) == 0) red[threadIdx.x >> 6] = s;
  __syncthreads();
  if (threadIdx.x == 0) {
    float t = red[0] + red[1] + red[2] + red[3];
    invn[row] = 1.f / fmaxf(sqrtf(t), 1e-12f);
  }
}

// ---------------- fused 16x16 channel attention per (b, head) ----------------
__global__ __launch_bounds__(256) void attn_kernel(const float* __restrict__ qd,
                                                   const float* __restrict__ kd,
                                                   const float* __restrict__ vd,
                                                   const float* __restrict__ invn,
                                                   const float* __restrict__ temp,
                                                   float* __restrict__ osb) {
  int bh = blockIdx.x;  // B*HEADS = 64
  int bi = bh >> 3;
  int h = bh & 7;
  int tid = threadIdx.x;
  int c = tid >> 4;
  int d = tid & 15;
  __shared__ float qs[16][65];
  __shared__ float ks[16][65];
  __shared__ float as[16][17];

  const float* qrow = qd + (size_t)(bi * C_ + h * CH_) * HW_;
  const float* krow = kd + (size_t)(bi * C_ + h * CH_) * HW_;
  float acc = 0.f;
  for (int n0 = 0; n0 < HW_; n0 += 64) {
    for (int l = tid; l < 1024; l += 256) {
      int r = l >> 6, j = l & 63;
      qs[r][j] = qrow[(size_t)r * HW_ + n0 + j];
      ks[r][j] = krow[(size_t)r * HW_ + n0 + j];
    }
    __syncthreads();
#pragma unroll
    for (int j = 0; j < 64; j++) acc = fmaf(qs[c][j], ks[d][j], acc);
    __syncthreads();
  }
  float S = acc * invn[bi * C_ + h * CH_ + c] * invn[1024 + bi * C_ + h * CH_ + d] *
            temp[h];
  // softmax over d (16 consecutive lanes per row c)
  float mx = S;
#pragma unroll
  for (int o = 8; o >= 1; o >>= 1) mx = fmaxf(mx, __shfl_xor(mx, o, 16));
  float e = expf(S - mx);
  float sm = e;
#pragma unroll
  for (int o = 8; o >= 1; o >>= 1) sm += __shfl_xor(sm, o, 16);
  as[c][d] = e / sm;
  __syncthreads();

  const float* vrow = vd + (size_t)(bi * C_ + h * CH_) * HW_;
  float* ob = osb + (size_t)(bi * C_ + h * CH_) * HW_;
  for (int n = tid; n < HW_; n += 256) {
    float o_[16];
#pragma unroll
    for (int cc = 0; cc < 16; cc++) o_[cc] = 0.f;
#pragma unroll
    for (int dd = 0; dd < 16; dd++) {
      float vv = vrow[(size_t)dd * HW_ + n];
#pragma unroll
      for (int cc = 0; cc < 16; cc++) o_[cc] = fmaf(as[cc][dd], vv, o_[cc]);
    }
#pragma unroll
    for (int cc = 0; cc < 16; cc++) ob[(size_t)cc * HW_ + n] = o_[cc];
  }
}

// ---------------- fused FFN depthwise conv + GEGLU gate (bf16 in/out) ----------------
template <int K>
__global__ __launch_bounds__(256) void ffn_dwgate(const __hip_bfloat16* __restrict__ xin,
                                                  const float* __restrict__ w,
                                                  __hip_bfloat16* __restrict__ gated) {
  int id = blockIdx.x * 256 + threadIdx.x;  // over B*512*HW
  int pos = id & (HW_ - 1);
  int xx = pos & (W_ - 1);
  int yy = pos >> 6;
  int bi_i = id >> 12;
  int i = bi_i & 511;
  int bi = bi_i >> 9;
  constexpr int P = K / 2;
  const __hip_bfloat16* gin = xin + (size_t)(bi * 1024 + i) * HW_;
  const __hip_bfloat16* min_ = xin + (size_t)(bi * 1024 + 512 + i) * HW_;
  const float* wg = w + i * K * K;
  const float* wm = w + (512 + i) * K * K;
  float g = 0.f, m = 0.f;
#pragma unroll
  for (int dy = 0; dy < K; dy++) {
    int y2 = yy + dy - P;
    if ((unsigned)y2 >= (unsigned)H_) continue;
#pragma unroll
    for (int dx = 0; dx < K; dx++) {
      int x2 = xx + dx - P;
      if ((unsigned)x2 >= (unsigned)W_) continue;
      g = fmaf(toF(gin[y2 * W_ + x2]), wg[dy * K + dx], g);
      m = fmaf(toF(min_[y2 * W_ + x2]), wm[dy * K + dx], m);
    }
  }
  float ge = 0.5f * g * (1.f + erff(g * 0.70710678118654752f));
  gated[(size_t)id] = __float2bfloat16(ge * m);
}

extern "C" void kernel_launch(void* const* d_in, const int* in_sizes, int n_in,
                              void* d_out, int out_size, void* d_ws, size_t ws_size,
                              hipStream_t stream) {
  const float* x = (const float*)d_in[0];
  const float* ln1_w = (const float*)d_in[1];
  const float* ln1_b = (const float*)d_in[2];
  const float* temp = (const float*)d_in[3];
  const float* wq = (const float*)d_in[4];
  const float* wk = (const float*)d_in[5];
  const float* wv = (const float*)d_in[6];
  const float* dw[9];
  for (int i = 0; i < 9; i++) dw[i] = (const float*)d_in[7 + i];  // q3,k3,v3,q5,k5,v5,q7,k7,v7
  const float* attn_po = (const float*)d_in[16];
  const float* ln2_w = (const float*)d_in[17];
  const float* ln2_b = (const float*)d_in[18];
  const float* ffn_in = (const float*)d_in[19];
  const float* ffn_dw[3] = {(const float*)d_in[20], (const float*)d_in[21],
                            (const float*)d_in[22]};
  const float* ffn_po = (const float*)d_in[23];
  float* out = (float*)d_out;

  // ---- workspace layout: peak 128 MiB + 8 KiB, lifetime-aliased ----
  const size_t MB = (size_t)1 << 20;
  char* wsb = (char*)d_ws;
  float* xn = (float*)(wsb + 0 * MB);    // attn LN out; later osb; later FFN LN out
  float* q0 = (float*)(wsb + 16 * MB);
  float* k0 = (float*)(wsb + 32 * MB);
  float* v0 = (float*)(wsb + 48 * MB);
  float* qd = (float*)(wsb + 64 * MB);
  float* kd = (float*)(wsb + 80 * MB);
  float* vd = (float*)(wsb + 96 * MB);
  float* x2 = (float*)(wsb + 112 * MB);
  float* invn = (float*)(wsb + 128 * MB);  // 8 KiB
  float* osb = xn;                          // attn per-scale output (aliases xn)
  float* xn2 = xn;                          // FFN LN out (aliases xn)
  __hip_bfloat16* xin = (__hip_bfloat16*)(wsb + 16 * MB);    // 64 MB, aliases q0..qd
  __hip_bfloat16* gated = (__hip_bfloat16*)(wsb + 80 * MB);  // 32 MB, aliases kd,vd

  const int ln_grid = (B_ * HW_) / 256;                  // 128
  const int c128_grid = B_ * (C_ / 8) * (HW_ / 256);     // 2048
  const int dwc_grid = B_ * C_ * HW_ / 256;              // 16384
  const int c1024_grid = B_ * (1024 / 8) * (HW_ / 256);  // 16384
  const int dwg_grid = B_ * 512 * HW_ / 256;             // 65536

  // ---- attention branch ----
  ln_ch<<<ln_grid, 256, 0, stream>>>(x, ln1_w, ln1_b, xn);
  conv1x1_k<float, float><<<c128_grid, 256, 0, stream>>>(xn, wq, nullptr, q0, C_, C_, C_, 0);
  conv1x1_k<float, float><<<c128_grid, 256, 0, stream>>>(xn, wk, nullptr, k0, C_, C_, C_, 0);
  conv1x1_k<float, float><<<c128_grid, 256, 0, stream>>>(xn, wv, nullptr, v0, C_, C_, C_, 0);

  for (int s = 0; s < 3; s++) {
    if (s == 0) {
      dwconv_k<3><<<dwc_grid, 256, 0, stream>>>(q0, dw[0], qd);
      dwconv_k<3><<<dwc_grid, 256, 0, stream>>>(k0, dw[1], kd);
      dwconv_k<3><<<dwc_grid, 256, 0, stream>>>(v0, dw[2], vd);
    } else if (s == 1) {
      dwconv_k<5><<<dwc_grid, 256, 0, stream>>>(q0, dw[3], qd);
      dwconv_k<5><<<dwc_grid, 256, 0, stream>>>(k0, dw[4], kd);
      dwconv_k<5><<<dwc_grid, 256, 0, stream>>>(v0, dw[5], vd);
    } else {
      dwconv_k<7><<<dwc_grid, 256, 0, stream>>>(q0, dw[6], qd);
      dwconv_k<7><<<dwc_grid, 256, 0, stream>>>(k0, dw[7], kd);
      dwconv_k<7><<<dwc_grid, 256, 0, stream>>>(v0, dw[8], vd);
    }
    l2_invnorm<<<2048, 256, 0, stream>>>(qd, kd, invn);
    attn_kernel<<<B_ * HEADS_, 256, 0, stream>>>(qd, kd, vd, invn, temp, osb);
    // x2 (s=0): x + po_s @ osb ; else x2 += po_s @ osb
    conv1x1_k<float, float><<<c128_grid, 256, 0, stream>>>(
        osb, attn_po + s * C_, (s == 0) ? x : nullptr, x2, C_, C_, 3 * C_,
        s == 0 ? 0 : 1);
  }

  // ---- FFN branch ----
  ln_ch<<<ln_grid, 256, 0, stream>>>(x2, ln2_w, ln2_b, xn2);
  conv1x1_k<float, __hip_bfloat16><<<c1024_grid, 256, 0, stream>>>(
      xn2, ffn_in, nullptr, xin, C_, 1024, C_, 0);

  for (int s = 0; s < 3; s++) {
    if (s == 0)
      ffn_dwgate<3><<<dwg_grid, 256, 0, stream>>>(xin, ffn_dw[0], gated);
    else if (s == 1)
      ffn_dwgate<5><<<dwg_grid, 256, 0, stream>>>(xin, ffn_dw[1], gated);
    else
      ffn_dwgate<7><<<dwg_grid, 256, 0, stream>>>(xin, ffn_dw[2], gated);
    // out (s=0): x2 + po_s @ gated ; else out += po_s @ gated
    conv1x1_k<__hip_bfloat16, float><<<c128_grid, 256, 0, stream>>>(
        gated, ffn_po + s * 512, (s == 0) ? x2 : nullptr, out, 512, C_, 3 * HID_,
        s == 0 ? 0 : 1);
  }
  (void)in_sizes; (void)n_in; (void)out_size; (void)ws_size;
}

// Round 3
// 1967.105 us; speedup vs baseline: 1.7647x; 1.7647x over previous
//
#include <hip/hip_runtime.h>
#include <hip/hip_bf16.h>
#include <math.h>

#define B_ 8
#define C_ 128
#define H_ 64
#define W_ 64
#define HW_ 4096
#define HEADS_ 8
#define CH_ 16
#define HID_ 512

typedef unsigned short ushort_t;
struct us4 { ushort_t x, y, z, w; };

__device__ __forceinline__ float bf2f(ushort_t u) {
  return __uint_as_float(((unsigned int)u) << 16);
}
__device__ __forceinline__ ushort_t f2bu(float f) {
  __hip_bfloat16 h = __float2bfloat16(f);
  return *reinterpret_cast<ushort_t*>(&h);
}
__device__ __forceinline__ float toF(float v) { return v; }
__device__ __forceinline__ float toF(__hip_bfloat16 v) { return __bfloat162float(v); }

// ---------------- LayerNorm over channel dim ----------------
__global__ __launch_bounds__(256) void ln_ch(const float* __restrict__ x,
                                             const float* __restrict__ w,
                                             const float* __restrict__ b,
                                             float* __restrict__ out) {
  int p = blockIdx.x * 256 + threadIdx.x;  // over B*HW
  int bi = p >> 12;
  int pos = p & (HW_ - 1);
  const float* xb = x + (size_t)bi * C_ * HW_ + pos;
  float s = 0.f, ss = 0.f;
  for (int c = 0; c < C_; c++) {
    float v = xb[(size_t)c * HW_];
    s += v;
    ss = fmaf(v, v, ss);
  }
  float mu = s * (1.f / C_);
  float var = ss * (1.f / C_) - mu * mu;
  float inv = rsqrtf(var + 1e-5f);
  float* ob = out + (size_t)bi * C_ * HW_ + pos;
  for (int c = 0; c < C_; c++) {
    ob[(size_t)c * HW_] = (xb[(size_t)c * HW_] - mu) * inv * w[c] + b[c];
  }
}

// ---------------- conv1x1 (GEMM over channels), 8 outputs x 4 positions ----------------
__device__ __forceinline__ void load4f(const float* p, float* v) {
  float4 t = *(const float4*)p;
  v[0] = t.x; v[1] = t.y; v[2] = t.z; v[3] = t.w;
}
__device__ __forceinline__ void load4f(const __hip_bfloat16* p, float* v) {
  us4 t = *(const us4*)p;
  v[0] = bf2f(t.x); v[1] = bf2f(t.y); v[2] = bf2f(t.z); v[3] = bf2f(t.w);
}
__device__ __forceinline__ void store4f(float* p, const float* v) {
  float4 t; t.x = v[0]; t.y = v[1]; t.z = v[2]; t.w = v[3];
  *(float4*)p = t;
}
__device__ __forceinline__ void store4f(__hip_bfloat16* p, const float* v) {
  us4 t; t.x = f2bu(v[0]); t.y = f2bu(v[1]); t.z = f2bu(v[2]); t.w = f2bu(v[3]);
  *(us4*)p = t;
}

template <typename Tin, typename Tout>
__global__ __launch_bounds__(256) void conv1x1_v(const Tin* __restrict__ in,
                                                 const float* __restrict__ wt,
                                                 const float* __restrict__ resid,
                                                 Tout* __restrict__ out,
                                                 int cin, int cout, int wstride,
                                                 int accum) {
  int tid = threadIdx.x;
  int blk = blockIdx.x;
  int pb = blk & 3;  // HW_/1024 = 4 position blocks
  int t = blk >> 2;
  int nob = cout >> 3;
  int ob = t % nob;
  int bi = t / nob;
  int pos = (pb << 10) + tid * 4;
  int o0 = ob << 3;
  const Tin* ib = in + (size_t)bi * cin * HW_ + pos;
  float acc[8][4] = {};
  for (int c = 0; c < cin; c++) {
    float xv[4];
    load4f(ib + (size_t)c * HW_, xv);
    const float* wr = wt + (size_t)o0 * wstride + c;
#pragma unroll
    for (int j = 0; j < 8; j++) {
      float wv = wr[(size_t)j * wstride];
      acc[j][0] = fmaf(wv, xv[0], acc[j][0]);
      acc[j][1] = fmaf(wv, xv[1], acc[j][1]);
      acc[j][2] = fmaf(wv, xv[2], acc[j][2]);
      acc[j][3] = fmaf(wv, xv[3], acc[j][3]);
    }
  }
  Tout* op = out + ((size_t)bi * cout + o0) * HW_ + pos;
  const float* rp = resid ? resid + ((size_t)bi * cout + o0) * HW_ + pos : nullptr;
#pragma unroll
  for (int j = 0; j < 8; j++) {
    float v[4];
    v[0] = acc[j][0]; v[1] = acc[j][1]; v[2] = acc[j][2]; v[3] = acc[j][3];
    if (rp) {
      float rv[4];
      load4f(rp + (size_t)j * HW_, rv);
      for (int q = 0; q < 4; q++) v[q] += rv[q];
    }
    if (accum) {
      float ov[4];
      load4f(op + (size_t)j * HW_, ov);
      for (int q = 0; q < 4; q++) v[q] += ov[q];
    }
    store4f(op + (size_t)j * HW_, v);
  }
}

// ---------------- LDS-tiled depthwise conv (q,k,v fused via blockIdx.y) ----------------
template <int K>
__global__ __launch_bounds__(256) void dwconv_t(const float* __restrict__ q0,
                                                const float* __restrict__ k0,
                                                const float* __restrict__ v0,
                                                const float* __restrict__ wq_,
                                                const float* __restrict__ wk_,
                                                const float* __restrict__ wv_,
                                                float* __restrict__ qd,
                                                float* __restrict__ kd,
                                                float* __restrict__ vd) {
  constexpr int P = K / 2;
  constexpr int PH = 64 + 2 * P;
  constexpr int ST = 64 + 2 * P + 1;  // odd stride -> bank-conflict-free
  __shared__ float img[PH * ST];
  __shared__ float wsh[K * K];
  int sel = blockIdx.y;
  const float* in = (sel == 0) ? q0 : (sel == 1) ? k0 : v0;
  const float* wgt = (sel == 0) ? wq_ : (sel == 1) ? wk_ : wv_;
  float* outp = (sel == 0) ? qd : (sel == 1) ? kd : vd;
  int blk = blockIdx.x;  // B*C
  int c = blk & (C_ - 1);
  int bi = blk >> 7;
  int tid = threadIdx.x;

  for (int l = tid; l < PH * ST; l += 256) img[l] = 0.f;
  if (tid < K * K) wsh[tid] = wgt[(size_t)c * K * K + tid];
  __syncthreads();

  const float* ib = in + (size_t)(bi * C_ + c) * HW_;
#pragma unroll
  for (int it = 0; it < 4; it++) {
    int idx = tid + it * 256;  // 0..1023, r = idx>>4, quad = idx&15
    int r = idx >> 4, q = idx & 15;
    float4 v = ((const float4*)ib)[idx];
    float* d = &img[(r + P) * ST + P + q * 4];
    d[0] = v.x; d[1] = v.y; d[2] = v.z; d[3] = v.w;
  }
  __syncthreads();

  int r = tid >> 2;
  int cb = (tid & 3) << 4;
  float a[16];
#pragma unroll
  for (int o = 0; o < 16; o++) a[o] = 0.f;
#pragma unroll
  for (int dy = 0; dy < K; dy++) {
    const float* row = &img[(r + dy) * ST + cb];
    float rv[16 + 2 * P];
#pragma unroll
    for (int t = 0; t < 16 + 2 * P; t++) rv[t] = row[t];
#pragma unroll
    for (int dx = 0; dx < K; dx++) {
      float wv = wsh[dy * K + dx];
#pragma unroll
      for (int o = 0; o < 16; o++) a[o] = fmaf(rv[o + dx], wv, a[o]);
    }
  }
  float* ob = outp + (size_t)(bi * C_ + c) * HW_ + r * 64 + cb;
#pragma unroll
  for (int v = 0; v < 4; v++) store4f(ob + v * 4, &a[v * 4]);
}

// ---------------- LDS-tiled fused FFN depthwise conv + GEGLU gate ----------------
template <int K>
__global__ __launch_bounds__(256) void ffn_dwgate_t(const __hip_bfloat16* __restrict__ xin,
                                                    const float* __restrict__ w,
                                                    __hip_bfloat16* __restrict__ gated) {
  constexpr int P = K / 2;
  constexpr int PH = 64 + 2 * P;
  constexpr int ST = 64 + 2 * P + 1;
  __shared__ float gs[PH * ST];
  __shared__ float ms[PH * ST];
  __shared__ float wsh[2 * K * K];
  int blk = blockIdx.x;  // B*512
  int i = blk & 511;
  int bi = blk >> 9;
  int tid = threadIdx.x;

  for (int l = tid; l < PH * ST; l += 256) { gs[l] = 0.f; ms[l] = 0.f; }
  if (tid < 2 * K * K) {
    wsh[tid] = (tid < K * K) ? w[(size_t)i * K * K + tid]
                             : w[(size_t)(512 + i) * K * K + (tid - K * K)];
  }
  __syncthreads();

  const __hip_bfloat16* gin = xin + (size_t)(bi * 1024 + i) * HW_;
  const __hip_bfloat16* min_ = xin + (size_t)(bi * 1024 + 512 + i) * HW_;
#pragma unroll
  for (int it = 0; it < 4; it++) {
    int idx = tid + it * 256;
    int r = idx >> 4, q = idx & 15;
    us4 gv = ((const us4*)gin)[idx];
    us4 mv = ((const us4*)min_)[idx];
    float* gd = &gs[(r + P) * ST + P + q * 4];
    float* md = &ms[(r + P) * ST + P + q * 4];
    gd[0] = bf2f(gv.x); gd[1] = bf2f(gv.y); gd[2] = bf2f(gv.z); gd[3] = bf2f(gv.w);
    md[0] = bf2f(mv.x); md[1] = bf2f(mv.y); md[2] = bf2f(mv.z); md[3] = bf2f(mv.w);
  }
  __syncthreads();

  int r = tid >> 2;
  int cb = (tid & 3) << 4;
  float ga[16], ma[16];
#pragma unroll
  for (int o = 0; o < 16; o++) { ga[o] = 0.f; ma[o] = 0.f; }
#pragma unroll
  for (int dy = 0; dy < K; dy++) {
    const float* grow = &gs[(r + dy) * ST + cb];
    const float* mrow = &ms[(r + dy) * ST + cb];
    float rg[16 + 2 * P], rm[16 + 2 * P];
#pragma unroll
    for (int t = 0; t < 16 + 2 * P; t++) { rg[t] = grow[t]; rm[t] = mrow[t]; }
#pragma unroll
    for (int dx = 0; dx < K; dx++) {
      float wgv = wsh[dy * K + dx];
      float wmv = wsh[K * K + dy * K + dx];
#pragma unroll
      for (int o = 0; o < 16; o++) {
        ga[o] = fmaf(rg[o + dx], wgv, ga[o]);
        ma[o] = fmaf(rm[o + dx], wmv, ma[o]);
      }
    }
  }
  __hip_bfloat16* gp = gated + (size_t)(bi * 512 + i) * HW_ + r * 64 + cb;
#pragma unroll
  for (int v = 0; v < 4; v++) {
    us4 t;
    float g0 = ga[v * 4 + 0], g1 = ga[v * 4 + 1], g2 = ga[v * 4 + 2], g3 = ga[v * 4 + 3];
    float e0 = 0.5f * g0 * (1.f + erff(g0 * 0.70710678118654752f));
    float e1 = 0.5f * g1 * (1.f + erff(g1 * 0.70710678118654752f));
    float e2 = 0.5f * g2 * (1.f + erff(g2 * 0.70710678118654752f));
    float e3 = 0.5f * g3 * (1.f + erff(g3 * 0.70710678118654752f));
    t.x = f2bu(e0 * ma[v * 4 + 0]);
    t.y = f2bu(e1 * ma[v * 4 + 1]);
    t.z = f2bu(e2 * ma[v * 4 + 2]);
    t.w = f2bu(e3 * ma[v * 4 + 3]);
    *(us4*)(gp + v * 4) = t;
  }
}

// ---------------- inverse L2 norms of qd and kd rows ----------------
__global__ __launch_bounds__(256) void l2_invnorm(const float* __restrict__ qd,
                                                  const float* __restrict__ kd,
                                                  float* __restrict__ invn) {
  int row = blockIdx.x;  // 0..2047; <1024 -> qd, else kd
  const float* src = (row < 1024) ? (qd + (size_t)row * HW_)
                                  : (kd + (size_t)(row - 1024) * HW_);
  float s = 0.f;
  for (int n = threadIdx.x; n < HW_; n += 256) {
    float v = src[n];
    s = fmaf(v, v, s);
  }
#pragma unroll
  for (int o = 32; o >= 1; o >>= 1) s += __shfl_xor(s, o, 64);
  __shared__ float red[4];
  if ((threadIdx.x & 63) == 0) red[threadIdx.x >> 6] = s;
  __syncthreads();
  if (threadIdx.x == 0) {
    float t = red[0] + red[1] + red[2] + red[3];
    invn[row] = 1.f / fmaxf(sqrtf(t), 1e-12f);
  }
}

// ---------------- fused 16x16 channel attention per (b, head) ----------------
__global__ __launch_bounds__(256) void attn_kernel(const float* __restrict__ qd,
                                                   const float* __restrict__ kd,
                                                   const float* __restrict__ vd,
                                                   const float* __restrict__ invn,
                                                   const float* __restrict__ temp,
                                                   float* __restrict__ osb) {
  int bh = blockIdx.x;  // B*HEADS = 64
  int bi = bh >> 3;
  int h = bh & 7;
  int tid = threadIdx.x;
  int c = tid >> 4;
  int d = tid & 15;
  __shared__ float qs[16][65];
  __shared__ float ks[16][65];
  __shared__ float as[16][17];

  const float* qrow = qd + (size_t)(bi * C_ + h * CH_) * HW_;
  const float* krow = kd + (size_t)(bi * C_ + h * CH_) * HW_;
  float acc = 0.f;
  for (int n0 = 0; n0 < HW_; n0 += 64) {
    for (int l = tid; l < 1024; l += 256) {
      int r = l >> 6, j = l & 63;
      qs[r][j] = qrow[(size_t)r * HW_ + n0 + j];
      ks[r][j] = krow[(size_t)r * HW_ + n0 + j];
    }
    __syncthreads();
#pragma unroll
    for (int j = 0; j < 64; j++) acc = fmaf(qs[c][j], ks[d][j], acc);
    __syncthreads();
  }
  float S = acc * invn[bi * C_ + h * CH_ + c] * invn[1024 + bi * C_ + h * CH_ + d] *
            temp[h];
  float mx = S;
#pragma unroll
  for (int o = 8; o >= 1; o >>= 1) mx = fmaxf(mx, __shfl_xor(mx, o, 16));
  float e = expf(S - mx);
  float sm = e;
#pragma unroll
  for (int o = 8; o >= 1; o >>= 1) sm += __shfl_xor(sm, o, 16);
  as[c][d] = e / sm;
  __syncthreads();

  const float* vrow = vd + (size_t)(bi * C_ + h * CH_) * HW_;
  float* ob = osb + (size_t)(bi * C_ + h * CH_) * HW_;
  for (int n = tid; n < HW_; n += 256) {
    float o_[16];
#pragma unroll
    for (int cc = 0; cc < 16; cc++) o_[cc] = 0.f;
#pragma unroll
    for (int dd = 0; dd < 16; dd++) {
      float vv = vrow[(size_t)dd * HW_ + n];
#pragma unroll
      for (int cc = 0; cc < 16; cc++) o_[cc] = fmaf(as[cc][dd], vv, o_[cc]);
    }
#pragma unroll
    for (int cc = 0; cc < 16; cc++) ob[(size_t)cc * HW_ + n] = o_[cc];
  }
}

extern "C" void kernel_launch(void* const* d_in, const int* in_sizes, int n_in,
                              void* d_out, int out_size, void* d_ws, size_t ws_size,
                              hipStream_t stream) {
  const float* x = (const float*)d_in[0];
  const float* ln1_w = (const float*)d_in[1];
  const float* ln1_b = (const float*)d_in[2];
  const float* temp = (const float*)d_in[3];
  const float* wq = (const float*)d_in[4];
  const float* wk = (const float*)d_in[5];
  const float* wv = (const float*)d_in[6];
  const float* dw[9];
  for (int i = 0; i < 9; i++) dw[i] = (const float*)d_in[7 + i];  // q3,k3,v3,q5,k5,v5,q7,k7,v7
  const float* attn_po = (const float*)d_in[16];
  const float* ln2_w = (const float*)d_in[17];
  const float* ln2_b = (const float*)d_in[18];
  const float* ffn_in = (const float*)d_in[19];
  const float* ffn_dw[3] = {(const float*)d_in[20], (const float*)d_in[21],
                            (const float*)d_in[22]};
  const float* ffn_po = (const float*)d_in[23];
  float* out = (float*)d_out;

  // ---- workspace layout: peak 128 MiB + 8 KiB, lifetime-aliased ----
  const size_t MB = (size_t)1 << 20;
  char* wsb = (char*)d_ws;
  float* xn = (float*)(wsb + 0 * MB);
  float* q0 = (float*)(wsb + 16 * MB);
  float* k0 = (float*)(wsb + 32 * MB);
  float* v0 = (float*)(wsb + 48 * MB);
  float* qd = (float*)(wsb + 64 * MB);
  float* kd = (float*)(wsb + 80 * MB);
  float* vd = (float*)(wsb + 96 * MB);
  float* x2 = (float*)(wsb + 112 * MB);
  float* invn = (float*)(wsb + 128 * MB);  // 8 KiB
  float* osb = xn;
  float* xn2 = xn;
  __hip_bfloat16* xin = (__hip_bfloat16*)(wsb + 16 * MB);    // 64 MB
  __hip_bfloat16* gated = (__hip_bfloat16*)(wsb + 80 * MB);  // 32 MB

  const int ln_grid = (B_ * HW_) / 256;                 // 128
  const int c128_grid = B_ * (C_ / 8) * (HW_ / 1024);   // 512
  const int c1024_grid = B_ * (1024 / 8) * (HW_ / 1024);// 4096
  const dim3 dwt_grid(B_ * C_, 3);                      // 1024 x 3
  const int ffg_grid = B_ * 512;                        // 4096

  // ---- attention branch ----
  ln_ch<<<ln_grid, 256, 0, stream>>>(x, ln1_w, ln1_b, xn);
  conv1x1_v<float, float><<<c128_grid, 256, 0, stream>>>(xn, wq, nullptr, q0, C_, C_, C_, 0);
  conv1x1_v<float, float><<<c128_grid, 256, 0, stream>>>(xn, wk, nullptr, k0, C_, C_, C_, 0);
  conv1x1_v<float, float><<<c128_grid, 256, 0, stream>>>(xn, wv, nullptr, v0, C_, C_, C_, 0);

  for (int s = 0; s < 3; s++) {
    if (s == 0)
      dwconv_t<3><<<dwt_grid, 256, 0, stream>>>(q0, k0, v0, dw[0], dw[1], dw[2], qd, kd, vd);
    else if (s == 1)
      dwconv_t<5><<<dwt_grid, 256, 0, stream>>>(q0, k0, v0, dw[3], dw[4], dw[5], qd, kd, vd);
    else
      dwconv_t<7><<<dwt_grid, 256, 0, stream>>>(q0, k0, v0, dw[6], dw[7], dw[8], qd, kd, vd);
    l2_invnorm<<<2048, 256, 0, stream>>>(qd, kd, invn);
    attn_kernel<<<B_ * HEADS_, 256, 0, stream>>>(qd, kd, vd, invn, temp, osb);
    conv1x1_v<float, float><<<c128_grid, 256, 0, stream>>>(
        osb, attn_po + s * C_, (s == 0) ? x : nullptr, x2, C_, C_, 3 * C_,
        s == 0 ? 0 : 1);
  }

  // ---- FFN branch ----
  ln_ch<<<ln_grid, 256, 0, stream>>>(x2, ln2_w, ln2_b, xn2);
  conv1x1_v<float, __hip_bfloat16><<<c1024_grid, 256, 0, stream>>>(
      xn2, ffn_in, nullptr, xin, C_, 1024, C_, 0);

  for (int s = 0; s < 3; s++) {
    if (s == 0)
      ffn_dwgate_t<3><<<ffg_grid, 256, 0, stream>>>(xin, ffn_dw[0], gated);
    else if (s == 1)
      ffn_dwgate_t<5><<<ffg_grid, 256, 0, stream>>>(xin, ffn_dw[1], gated);
    else
      ffn_dwgate_t<7><<<ffg_grid, 256, 0, stream>>>(xin, ffn_dw[2], gated);
    conv1x1_v<__hip_bfloat16, float><<<c128_grid, 256, 0, stream>>>(
        gated, ffn_po + s * 512, (s == 0) ? x2 : nullptr, out, 512, C_, 3 * HID_,
        s == 0 ? 0 : 1);
  }
  (void)in_sizes; (void)n_in; (void)out_size; (void)ws_size;
}

// Round 4
// 1661.436 us; speedup vs baseline: 2.0893x; 1.1840x over previous
//
#include <hip/hip_runtime.h>
#include <hip/hip_bf16.h>
#include <math.h>

#define B_ 8
#define C_ 128
#define H_ 64
#define W_ 64
#define HW_ 4096
#define HEADS_ 8
#define CH_ 16
#define HID_ 512

typedef unsigned short ushort_t;
struct us4 { ushort_t x, y, z, w; };

__device__ __forceinline__ float bf2f(ushort_t u) {
  return __uint_as_float(((unsigned int)u) << 16);
}
__device__ __forceinline__ ushort_t f2bu(float f) {
  __hip_bfloat16 h = __float2bfloat16(f);
  return *reinterpret_cast<ushort_t*>(&h);
}

// ---------------- LayerNorm over channel dim ----------------
__global__ __launch_bounds__(256) void ln_ch(const float* __restrict__ x,
                                             const float* __restrict__ w,
                                             const float* __restrict__ b,
                                             float* __restrict__ out) {
  int p = blockIdx.x * 256 + threadIdx.x;  // over B*HW
  int bi = p >> 12;
  int pos = p & (HW_ - 1);
  const float* xb = x + (size_t)bi * C_ * HW_ + pos;
  float s = 0.f, ss = 0.f;
  for (int c = 0; c < C_; c++) {
    float v = xb[(size_t)c * HW_];
    s += v;
    ss = fmaf(v, v, ss);
  }
  float mu = s * (1.f / C_);
  float var = ss * (1.f / C_) - mu * mu;
  float inv = rsqrtf(var + 1e-5f);
  float* ob = out + (size_t)bi * C_ * HW_ + pos;
  for (int c = 0; c < C_; c++) {
    ob[(size_t)c * HW_] = (xb[(size_t)c * HW_] - mu) * inv * w[c] + b[c];
  }
}

// ---------------- vector load/store helpers ----------------
__device__ __forceinline__ void load4f(const float* p, float* v) {
  float4 t = *(const float4*)p;
  v[0] = t.x; v[1] = t.y; v[2] = t.z; v[3] = t.w;
}
__device__ __forceinline__ void load4f(const __hip_bfloat16* p, float* v) {
  us4 t = *(const us4*)p;
  v[0] = bf2f(t.x); v[1] = bf2f(t.y); v[2] = bf2f(t.z); v[3] = bf2f(t.w);
}
__device__ __forceinline__ void store4f(float* p, const float* v) {
  float4 t; t.x = v[0]; t.y = v[1]; t.z = v[2]; t.w = v[3];
  *(float4*)p = t;
}
__device__ __forceinline__ void store4f(__hip_bfloat16* p, const float* v) {
  us4 t; t.x = f2bu(v[0]); t.y = f2bu(v[1]); t.z = f2bu(v[2]); t.w = f2bu(v[3]);
  *(us4*)p = t;
}

// ------- conv1x1 (GEMM over channels), 16 outputs x 4 positions, LDS weights -------
template <int CIN, typename Tin, typename Tout>
__global__ __launch_bounds__(256) void conv1x1_v(const Tin* __restrict__ in,
                                                 const float* __restrict__ wt,
                                                 const float* __restrict__ resid,
                                                 Tout* __restrict__ out,
                                                 int cout, int wstride, int accum) {
  __shared__ float wsh[CIN * 16];
  int tid = threadIdx.x;
  int blk = blockIdx.x;
  int pb = blk & 3;  // 4 position blocks of 1024
  int t = blk >> 2;
  int nob = cout >> 4;
  int ob = t % nob;
  int bi = t / nob;
  int pos = (pb << 10) + tid * 4;
  int o0 = ob << 4;
  // stage weight tile [c][16] (linear LDS writes)
  for (int l = tid; l < CIN * 16; l += 256) {
    int c = l >> 4, j = l & 15;
    wsh[l] = wt[(size_t)(o0 + j) * wstride + c];
  }
  __syncthreads();

  const Tin* ib = in + (size_t)bi * CIN * HW_ + pos;
  float acc[16][4] = {};
#pragma unroll 4
  for (int c = 0; c < CIN; c++) {
    float xv[4];
    load4f(ib + (size_t)c * HW_, xv);
    const float* wr = &wsh[c * 16];
#pragma unroll
    for (int j = 0; j < 16; j++) {
      float wv = wr[j];
      acc[j][0] = fmaf(wv, xv[0], acc[j][0]);
      acc[j][1] = fmaf(wv, xv[1], acc[j][1]);
      acc[j][2] = fmaf(wv, xv[2], acc[j][2]);
      acc[j][3] = fmaf(wv, xv[3], acc[j][3]);
    }
  }
  Tout* op = out + ((size_t)bi * cout + o0) * HW_ + pos;
  const float* rp = resid ? resid + ((size_t)bi * cout + o0) * HW_ + pos : nullptr;
#pragma unroll
  for (int j = 0; j < 16; j++) {
    float v[4];
    v[0] = acc[j][0]; v[1] = acc[j][1]; v[2] = acc[j][2]; v[3] = acc[j][3];
    if (rp) {
      float rv[4];
      load4f(rp + (size_t)j * HW_, rv);
      for (int q = 0; q < 4; q++) v[q] += rv[q];
    }
    if (accum) {
      float ov[4];
      load4f(op + (size_t)j * HW_, ov);
      for (int q = 0; q < 4; q++) v[q] += ov[q];
    }
    store4f(op + (size_t)j * HW_, v);
  }
}

// ---------------- LDS-tiled depthwise conv (q,k,v fused via blockIdx.y) ----------------
template <int K>
__global__ __launch_bounds__(256) void dwconv_t(const float* __restrict__ q0,
                                                const float* __restrict__ k0,
                                                const float* __restrict__ v0,
                                                const float* __restrict__ wq_,
                                                const float* __restrict__ wk_,
                                                const float* __restrict__ wv_,
                                                float* __restrict__ qd,
                                                float* __restrict__ kd,
                                                float* __restrict__ vd) {
  constexpr int P = K / 2;
  constexpr int PH = 64 + 2 * P;
  constexpr int ST = 64 + 2 * P + 1;  // odd stride -> conflict-light
  __shared__ float img[PH * ST];
  __shared__ float wsh[K * K];
  int sel = blockIdx.y;
  const float* in = (sel == 0) ? q0 : (sel == 1) ? k0 : v0;
  const float* wgt = (sel == 0) ? wq_ : (sel == 1) ? wk_ : wv_;
  float* outp = (sel == 0) ? qd : (sel == 1) ? kd : vd;
  int blk = blockIdx.x;  // B*C
  int c = blk & (C_ - 1);
  int bi = blk >> 7;
  int tid = threadIdx.x;

  for (int l = tid; l < PH * ST; l += 256) img[l] = 0.f;
  if (tid < K * K) wsh[tid] = wgt[(size_t)c * K * K + tid];
  __syncthreads();

  const float* ib = in + (size_t)(bi * C_ + c) * HW_;
#pragma unroll
  for (int it = 0; it < 4; it++) {
    int idx = tid + it * 256;
    int r = idx >> 4, q = idx & 15;
    float4 v = ((const float4*)ib)[idx];
    float* d = &img[(r + P) * ST + P + q * 4];
    d[0] = v.x; d[1] = v.y; d[2] = v.z; d[3] = v.w;
  }
  __syncthreads();

  int r = tid >> 2;
  int cb = (tid & 3) << 4;
  float a[16];
#pragma unroll
  for (int o = 0; o < 16; o++) a[o] = 0.f;
#pragma unroll
  for (int dy = 0; dy < K; dy++) {
    const float* row = &img[(r + dy) * ST + cb];
    float rv[16 + 2 * P];
#pragma unroll
    for (int t = 0; t < 16 + 2 * P; t++) rv[t] = row[t];
#pragma unroll
    for (int dx = 0; dx < K; dx++) {
      float wv = wsh[dy * K + dx];
#pragma unroll
      for (int o = 0; o < 16; o++) a[o] = fmaf(rv[o + dx], wv, a[o]);
    }
  }
  float* ob = outp + (size_t)(bi * C_ + c) * HW_ + r * 64 + cb;
#pragma unroll
  for (int v = 0; v < 4; v++) store4f(ob + v * 4, &a[v * 4]);
}

// ------- FFN depthwise conv + GEGLU gate, two-phase single LDS plane -------
template <int K>
__global__ __launch_bounds__(256) void ffn_dwgate_t(const __hip_bfloat16* __restrict__ xin,
                                                    const float* __restrict__ w,
                                                    __hip_bfloat16* __restrict__ gated) {
  constexpr int P = K / 2;
  constexpr int PH = 64 + 2 * P;
  constexpr int ST = 64 + 2 * P + 1;
  __shared__ float img[PH * ST];
  __shared__ float wsh[2 * K * K];
  int blk = blockIdx.x;  // B*512
  int i = blk & 511;
  int bi = blk >> 9;
  int tid = threadIdx.x;

  if (tid < 2 * K * K) {
    wsh[tid] = (tid < K * K) ? w[(size_t)i * K * K + tid]
                             : w[(size_t)(512 + i) * K * K + (tid - K * K)];
  }
  for (int l = tid; l < PH * ST; l += 256) img[l] = 0.f;
  __syncthreads();

  const __hip_bfloat16* gin = xin + (size_t)(bi * 1024 + i) * HW_;
  const __hip_bfloat16* min_ = gin + (size_t)512 * HW_;
  int r = tid >> 2;
  int cb = (tid & 3) << 4;

  // ---- phase 1: gate plane ----
#pragma unroll
  for (int it = 0; it < 4; it++) {
    int idx = tid + it * 256;
    int rr = idx >> 4, q = idx & 15;
    us4 gv = ((const us4*)gin)[idx];
    float* gd = &img[(rr + P) * ST + P + q * 4];
    gd[0] = bf2f(gv.x); gd[1] = bf2f(gv.y); gd[2] = bf2f(gv.z); gd[3] = bf2f(gv.w);
  }
  __syncthreads();

  float ge[16];
  {
    float a[16];
#pragma unroll
    for (int o = 0; o < 16; o++) a[o] = 0.f;
#pragma unroll
    for (int dy = 0; dy < K; dy++) {
      const float* row = &img[(r + dy) * ST + cb];
      float rv[16 + 2 * P];
#pragma unroll
      for (int t = 0; t < 16 + 2 * P; t++) rv[t] = row[t];
#pragma unroll
      for (int dx = 0; dx < K; dx++) {
        float wv = wsh[dy * K + dx];
#pragma unroll
        for (int o = 0; o < 16; o++) a[o] = fmaf(rv[o + dx], wv, a[o]);
      }
    }
#pragma unroll
    for (int o = 0; o < 16; o++)
      ge[o] = 0.5f * a[o] * (1.f + erff(a[o] * 0.70710678118654752f));
  }
  __syncthreads();  // all reads of g-plane done

  // ---- phase 2: mult plane into same LDS (borders still zero) ----
#pragma unroll
  for (int it = 0; it < 4; it++) {
    int idx = tid + it * 256;
    int rr = idx >> 4, q = idx & 15;
    us4 mv = ((const us4*)min_)[idx];
    float* md = &img[(rr + P) * ST + P + q * 4];
    md[0] = bf2f(mv.x); md[1] = bf2f(mv.y); md[2] = bf2f(mv.z); md[3] = bf2f(mv.w);
  }
  __syncthreads();

  float ma[16];
#pragma unroll
  for (int o = 0; o < 16; o++) ma[o] = 0.f;
#pragma unroll
  for (int dy = 0; dy < K; dy++) {
    const float* row = &img[(r + dy) * ST + cb];
    float rv[16 + 2 * P];
#pragma unroll
    for (int t = 0; t < 16 + 2 * P; t++) rv[t] = row[t];
#pragma unroll
    for (int dx = 0; dx < K; dx++) {
      float wv = wsh[K * K + dy * K + dx];
#pragma unroll
      for (int o = 0; o < 16; o++) ma[o] = fmaf(rv[o + dx], wv, ma[o]);
    }
  }
  __hip_bfloat16* gp = gated + (size_t)(bi * 512 + i) * HW_ + r * 64 + cb;
#pragma unroll
  for (int v = 0; v < 4; v++) {
    us4 t;
    t.x = f2bu(ge[v * 4 + 0] * ma[v * 4 + 0]);
    t.y = f2bu(ge[v * 4 + 1] * ma[v * 4 + 1]);
    t.z = f2bu(ge[v * 4 + 2] * ma[v * 4 + 2]);
    t.w = f2bu(ge[v * 4 + 3] * ma[v * 4 + 3]);
    *(us4*)(gp + v * 4) = t;
  }
}

// ---------------- inverse L2 norms of qd and kd rows ----------------
__global__ __launch_bounds__(256) void l2_invnorm(const float* __restrict__ qd,
                                                  const float* __restrict__ kd,
                                                  float* __restrict__ invn) {
  int row = blockIdx.x;  // 0..2047; <1024 -> qd, else kd
  const float* src = (row < 1024) ? (qd + (size_t)row * HW_)
                                  : (kd + (size_t)(row - 1024) * HW_);
  float s = 0.f;
  for (int n = threadIdx.x; n < HW_; n += 256) {
    float v = src[n];
    s = fmaf(v, v, s);
  }
#pragma unroll
  for (int o = 32; o >= 1; o >>= 1) s += __shfl_xor(s, o, 64);
  __shared__ float red[4];
  if ((threadIdx.x & 63) == 0) red[threadIdx.x >> 6] = s;
  __syncthreads();
  if (threadIdx.x == 0) {
    float t = red[0] + red[1] + red[2] + red[3];
    invn[row] = 1.f / fmaxf(sqrtf(t), 1e-12f);
  }
}

// ---------------- fused 16x16 channel attention per (b, head) ----------------
__global__ __launch_bounds__(256) void attn_kernel(const float* __restrict__ qd,
                                                   const float* __restrict__ kd,
                                                   const float* __restrict__ vd,
                                                   const float* __restrict__ invn,
                                                   const float* __restrict__ temp,
                                                   float* __restrict__ osb) {
  int bh = blockIdx.x;  // B*HEADS = 64
  int bi = bh >> 3;
  int h = bh & 7;
  int tid = threadIdx.x;
  int c = tid >> 4;
  int d = tid & 15;
  __shared__ float qs[16][65];
  __shared__ float ks[16][65];
  __shared__ float as[16][17];

  const float* qrow = qd + (size_t)(bi * C_ + h * CH_) * HW_;
  const float* krow = kd + (size_t)(bi * C_ + h * CH_) * HW_;
  float acc = 0.f;
  for (int n0 = 0; n0 < HW_; n0 += 64) {
    for (int l = tid; l < 1024; l += 256) {
      int r = l >> 6, j = l & 63;
      qs[r][j] = qrow[(size_t)r * HW_ + n0 + j];
      ks[r][j] = krow[(size_t)r * HW_ + n0 + j];
    }
    __syncthreads();
#pragma unroll
    for (int j = 0; j < 64; j++) acc = fmaf(qs[c][j], ks[d][j], acc);
    __syncthreads();
  }
  float S = acc * invn[bi * C_ + h * CH_ + c] * invn[1024 + bi * C_ + h * CH_ + d] *
            temp[h];
  float mx = S;
#pragma unroll
  for (int o = 8; o >= 1; o >>= 1) mx = fmaxf(mx, __shfl_xor(mx, o, 16));
  float e = expf(S - mx);
  float sm = e;
#pragma unroll
  for (int o = 8; o >= 1; o >>= 1) sm += __shfl_xor(sm, o, 16);
  as[c][d] = e / sm;
  __syncthreads();

  const float* vrow = vd + (size_t)(bi * C_ + h * CH_) * HW_;
  float* ob = osb + (size_t)(bi * C_ + h * CH_) * HW_;
  for (int n = tid; n < HW_; n += 256) {
    float o_[16];
#pragma unroll
    for (int cc = 0; cc < 16; cc++) o_[cc] = 0.f;
#pragma unroll
    for (int dd = 0; dd < 16; dd++) {
      float vv = vrow[(size_t)dd * HW_ + n];
#pragma unroll
      for (int cc = 0; cc < 16; cc++) o_[cc] = fmaf(as[cc][dd], vv, o_[cc]);
    }
#pragma unroll
    for (int cc = 0; cc < 16; cc++) ob[(size_t)cc * HW_ + n] = o_[cc];
  }
}

extern "C" void kernel_launch(void* const* d_in, const int* in_sizes, int n_in,
                              void* d_out, int out_size, void* d_ws, size_t ws_size,
                              hipStream_t stream) {
  const float* x = (const float*)d_in[0];
  const float* ln1_w = (const float*)d_in[1];
  const float* ln1_b = (const float*)d_in[2];
  const float* temp = (const float*)d_in[3];
  const float* wq = (const float*)d_in[4];
  const float* wk = (const float*)d_in[5];
  const float* wv = (const float*)d_in[6];
  const float* dw[9];
  for (int i = 0; i < 9; i++) dw[i] = (const float*)d_in[7 + i];
  const float* attn_po = (const float*)d_in[16];
  const float* ln2_w = (const float*)d_in[17];
  const float* ln2_b = (const float*)d_in[18];
  const float* ffn_in = (const float*)d_in[19];
  const float* ffn_dw[3] = {(const float*)d_in[20], (const float*)d_in[21],
                            (const float*)d_in[22]};
  const float* ffn_po = (const float*)d_in[23];
  float* out = (float*)d_out;

  // ---- workspace layout: peak 128 MiB + 8 KiB, lifetime-aliased ----
  const size_t MB = (size_t)1 << 20;
  char* wsb = (char*)d_ws;
  float* xn = (float*)(wsb + 0 * MB);
  float* q0 = (float*)(wsb + 16 * MB);
  float* k0 = (float*)(wsb + 32 * MB);
  float* v0 = (float*)(wsb + 48 * MB);
  float* qd = (float*)(wsb + 64 * MB);
  float* kd = (float*)(wsb + 80 * MB);
  float* vd = (float*)(wsb + 96 * MB);
  float* x2 = (float*)(wsb + 112 * MB);
  float* invn = (float*)(wsb + 128 * MB);  // 8 KiB
  float* osb = xn;
  float* xn2 = xn;
  __hip_bfloat16* xin = (__hip_bfloat16*)(wsb + 16 * MB);    // 64 MB
  __hip_bfloat16* gated = (__hip_bfloat16*)(wsb + 80 * MB);  // 32 MB

  const int ln_grid = (B_ * HW_) / 256;                  // 128
  const int c128_grid = B_ * (C_ / 16) * 4;              // 256
  const int c1024_grid = B_ * (1024 / 16) * 4;           // 2048
  const dim3 dwt_grid(B_ * C_, 3);                       // 1024 x 3
  const int ffg_grid = B_ * 512;                         // 4096

  // ---- attention branch ----
  ln_ch<<<ln_grid, 256, 0, stream>>>(x, ln1_w, ln1_b, xn);
  conv1x1_v<C_, float, float><<<c128_grid, 256, 0, stream>>>(xn, wq, nullptr, q0, C_, C_, 0);
  conv1x1_v<C_, float, float><<<c128_grid, 256, 0, stream>>>(xn, wk, nullptr, k0, C_, C_, 0);
  conv1x1_v<C_, float, float><<<c128_grid, 256, 0, stream>>>(xn, wv, nullptr, v0, C_, C_, 0);

  for (int s = 0; s < 3; s++) {
    if (s == 0)
      dwconv_t<3><<<dwt_grid, 256, 0, stream>>>(q0, k0, v0, dw[0], dw[1], dw[2], qd, kd, vd);
    else if (s == 1)
      dwconv_t<5><<<dwt_grid, 256, 0, stream>>>(q0, k0, v0, dw[3], dw[4], dw[5], qd, kd, vd);
    else
      dwconv_t<7><<<dwt_grid, 256, 0, stream>>>(q0, k0, v0, dw[6], dw[7], dw[8], qd, kd, vd);
    l2_invnorm<<<2048, 256, 0, stream>>>(qd, kd, invn);
    attn_kernel<<<B_ * HEADS_, 256, 0, stream>>>(qd, kd, vd, invn, temp, osb);
    conv1x1_v<C_, float, float><<<c128_grid, 256, 0, stream>>>(
        osb, attn_po + s * C_, (s == 0) ? x : nullptr, x2, C_, 3 * C_, s == 0 ? 0 : 1);
  }

  // ---- FFN branch ----
  ln_ch<<<ln_grid, 256, 0, stream>>>(x2, ln2_w, ln2_b, xn2);
  conv1x1_v<C_, float, __hip_bfloat16><<<c1024_grid, 256, 0, stream>>>(
      xn2, ffn_in, nullptr, xin, 1024, C_, 0);

  for (int s = 0; s < 3; s++) {
    if (s == 0)
      ffn_dwgate_t<3><<<ffg_grid, 256, 0, stream>>>(xin, ffn_dw[0], gated);
    else if (s == 1)
      ffn_dwgate_t<5><<<ffg_grid, 256, 0, stream>>>(xin, ffn_dw[1], gated);
    else
      ffn_dwgate_t<7><<<ffg_grid, 256, 0, stream>>>(xin, ffn_dw[2], gated);
    conv1x1_v<512, __hip_bfloat16, float><<<c128_grid, 256, 0, stream>>>(
        gated, ffn_po + s * 512, (s == 0) ? x2 : nullptr, out, C_, 3 * HID_,
        s == 0 ? 0 : 1);
  }
  (void)in_sizes; (void)n_in; (void)out_size; (void)ws_size;
}

// Round 5
// 1134.980 us; speedup vs baseline: 3.0584x; 1.4638x over previous
//
#include <hip/hip_runtime.h>
#include <hip/hip_bf16.h>
#include <math.h>

#define B_ 8
#define C_ 128
#define H_ 64
#define W_ 64
#define HW_ 4096
#define HEADS_ 8
#define CH_ 16
#define HID_ 512

typedef unsigned short ushort_t;
struct us4 { ushort_t x, y, z, w; };

__device__ __forceinline__ float bf2f(ushort_t u) {
  return __uint_as_float(((unsigned int)u) << 16);
}
__device__ __forceinline__ ushort_t f2bu(float f) {
  __hip_bfloat16 h = __float2bfloat16(f);
  return *reinterpret_cast<ushort_t*>(&h);
}

// ---------------- LayerNorm over channel dim ----------------
__global__ __launch_bounds__(256) void ln_ch(const float* __restrict__ x,
                                             const float* __restrict__ w,
                                             const float* __restrict__ b,
                                             float* __restrict__ out) {
  int p = blockIdx.x * 256 + threadIdx.x;  // over B*HW
  int bi = p >> 12;
  int pos = p & (HW_ - 1);
  const float* xb = x + (size_t)bi * C_ * HW_ + pos;
  float s = 0.f, ss = 0.f;
  for (int c = 0; c < C_; c++) {
    float v = xb[(size_t)c * HW_];
    s += v;
    ss = fmaf(v, v, ss);
  }
  float mu = s * (1.f / C_);
  float var = ss * (1.f / C_) - mu * mu;
  float inv = rsqrtf(var + 1e-5f);
  float* ob = out + (size_t)bi * C_ * HW_ + pos;
  for (int c = 0; c < C_; c++) {
    ob[(size_t)c * HW_] = (xb[(size_t)c * HW_] - mu) * inv * w[c] + b[c];
  }
}

// ---------------- vector load/store helpers ----------------
__device__ __forceinline__ void load4f(const float* p, float* v) {
  float4 t = *(const float4*)p;
  v[0] = t.x; v[1] = t.y; v[2] = t.z; v[3] = t.w;
}
__device__ __forceinline__ void load4f(const __hip_bfloat16* p, float* v) {
  us4 t = *(const us4*)p;
  v[0] = bf2f(t.x); v[1] = bf2f(t.y); v[2] = bf2f(t.z); v[3] = bf2f(t.w);
}
__device__ __forceinline__ void store4f(float* p, const float* v) {
  float4 t; t.x = v[0]; t.y = v[1]; t.z = v[2]; t.w = v[3];
  *(float4*)p = t;
}
__device__ __forceinline__ void store4f(__hip_bfloat16* p, const float* v) {
  us4 t; t.x = f2bu(v[0]); t.y = f2bu(v[1]); t.z = f2bu(v[2]); t.w = f2bu(v[3]);
  *(us4*)p = t;
}

// ------- conv1x1 (GEMM over channels), 16 outputs x 4 positions, LDS weights -------
template <int CIN, typename Tin, typename Tout>
__global__ __launch_bounds__(256) void conv1x1_v(const Tin* __restrict__ in,
                                                 const float* __restrict__ wt,
                                                 const float* __restrict__ resid,
                                                 Tout* __restrict__ out,
                                                 int cout, int wstride, int accum) {
  __shared__ float wsh[CIN * 16];
  int tid = threadIdx.x;
  int blk = blockIdx.x;
  int pb = blk & 3;  // 4 position blocks of 1024
  int t = blk >> 2;
  int nob = cout >> 4;
  int ob = t % nob;
  int bi = t / nob;
  int pos = (pb << 10) + tid * 4;
  int o0 = ob << 4;
  for (int l = tid; l < CIN * 16; l += 256) {
    int c = l >> 4, j = l & 15;
    wsh[l] = wt[(size_t)(o0 + j) * wstride + c];
  }
  __syncthreads();

  const Tin* ib = in + (size_t)bi * CIN * HW_ + pos;
  float acc[16][4] = {};
#pragma unroll 4
  for (int c = 0; c < CIN; c++) {
    float xv[4];
    load4f(ib + (size_t)c * HW_, xv);
    const float* wr = &wsh[c * 16];
#pragma unroll
    for (int j = 0; j < 16; j++) {
      float wv = wr[j];
      acc[j][0] = fmaf(wv, xv[0], acc[j][0]);
      acc[j][1] = fmaf(wv, xv[1], acc[j][1]);
      acc[j][2] = fmaf(wv, xv[2], acc[j][2]);
      acc[j][3] = fmaf(wv, xv[3], acc[j][3]);
    }
  }
  Tout* op = out + ((size_t)bi * cout + o0) * HW_ + pos;
  const float* rp = resid ? resid + ((size_t)bi * cout + o0) * HW_ + pos : nullptr;
#pragma unroll
  for (int j = 0; j < 16; j++) {
    float v[4];
    v[0] = acc[j][0]; v[1] = acc[j][1]; v[2] = acc[j][2]; v[3] = acc[j][3];
    if (rp) {
      float rv[4];
      load4f(rp + (size_t)j * HW_, rv);
      for (int q = 0; q < 4; q++) v[q] += rv[q];
    }
    if (accum) {
      float ov[4];
      load4f(op + (size_t)j * HW_, ov);
      for (int q = 0; q < 4; q++) v[q] += ov[q];
    }
    store4f(op + (size_t)j * HW_, v);
  }
}

// ---------------- LDS-tiled depthwise conv (q,k,v fused via blockIdx.y) ----------------
template <int K>
__global__ __launch_bounds__(256) void dwconv_t(const float* __restrict__ q0,
                                                const float* __restrict__ k0,
                                                const float* __restrict__ v0,
                                                const float* __restrict__ wq_,
                                                const float* __restrict__ wk_,
                                                const float* __restrict__ wv_,
                                                float* __restrict__ qd,
                                                float* __restrict__ kd,
                                                float* __restrict__ vd) {
  constexpr int P = K / 2;
  constexpr int PH = 64 + 2 * P;
  constexpr int ST = 64 + 2 * P + 1;
  __shared__ float img[PH * ST];
  __shared__ float wsh[K * K];
  int sel = blockIdx.y;
  const float* in = (sel == 0) ? q0 : (sel == 1) ? k0 : v0;
  const float* wgt = (sel == 0) ? wq_ : (sel == 1) ? wk_ : wv_;
  float* outp = (sel == 0) ? qd : (sel == 1) ? kd : vd;
  int blk = blockIdx.x;  // B*C
  int c = blk & (C_ - 1);
  int bi = blk >> 7;
  int tid = threadIdx.x;

  for (int l = tid; l < PH * ST; l += 256) img[l] = 0.f;
  if (tid < K * K) wsh[tid] = wgt[(size_t)c * K * K + tid];
  __syncthreads();

  const float* ib = in + (size_t)(bi * C_ + c) * HW_;
#pragma unroll
  for (int it = 0; it < 4; it++) {
    int idx = tid + it * 256;
    int r = idx >> 4, q = idx & 15;
    float4 v = ((const float4*)ib)[idx];
    float* d = &img[(r + P) * ST + P + q * 4];
    d[0] = v.x; d[1] = v.y; d[2] = v.z; d[3] = v.w;
  }
  __syncthreads();

  int r = tid >> 2;
  int cb = (tid & 3) << 4;
  float a[16];
#pragma unroll
  for (int o = 0; o < 16; o++) a[o] = 0.f;
#pragma unroll
  for (int dy = 0; dy < K; dy++) {
    const float* row = &img[(r + dy) * ST + cb];
    float rv[16 + 2 * P];
#pragma unroll
    for (int t = 0; t < 16 + 2 * P; t++) rv[t] = row[t];
#pragma unroll
    for (int dx = 0; dx < K; dx++) {
      float wv = wsh[dy * K + dx];
#pragma unroll
      for (int o = 0; o < 16; o++) a[o] = fmaf(rv[o + dx], wv, a[o]);
    }
  }
  float* ob = outp + (size_t)(bi * C_ + c) * HW_ + r * 64 + cb;
#pragma unroll
  for (int v = 0; v < 4; v++) store4f(ob + v * 4, &a[v * 4]);
}

// ------- FFN depthwise conv + GEGLU gate, two-phase single LDS plane -------
template <int K>
__global__ __launch_bounds__(256) void ffn_dwgate_t(const __hip_bfloat16* __restrict__ xin,
                                                    const float* __restrict__ w,
                                                    __hip_bfloat16* __restrict__ gated) {
  constexpr int P = K / 2;
  constexpr int PH = 64 + 2 * P;
  constexpr int ST = 64 + 2 * P + 1;
  __shared__ float img[PH * ST];
  __shared__ float wsh[2 * K * K];
  int blk = blockIdx.x;  // B*512
  int i = blk & 511;
  int bi = blk >> 9;
  int tid = threadIdx.x;

  if (tid < 2 * K * K) {
    wsh[tid] = (tid < K * K) ? w[(size_t)i * K * K + tid]
                             : w[(size_t)(512 + i) * K * K + (tid - K * K)];
  }
  for (int l = tid; l < PH * ST; l += 256) img[l] = 0.f;
  __syncthreads();

  const __hip_bfloat16* gin = xin + (size_t)(bi * 1024 + i) * HW_;
  const __hip_bfloat16* min_ = gin + (size_t)512 * HW_;
  int r = tid >> 2;
  int cb = (tid & 3) << 4;

#pragma unroll
  for (int it = 0; it < 4; it++) {
    int idx = tid + it * 256;
    int rr = idx >> 4, q = idx & 15;
    us4 gv = ((const us4*)gin)[idx];
    float* gd = &img[(rr + P) * ST + P + q * 4];
    gd[0] = bf2f(gv.x); gd[1] = bf2f(gv.y); gd[2] = bf2f(gv.z); gd[3] = bf2f(gv.w);
  }
  __syncthreads();

  float ge[16];
  {
    float a[16];
#pragma unroll
    for (int o = 0; o < 16; o++) a[o] = 0.f;
#pragma unroll
    for (int dy = 0; dy < K; dy++) {
      const float* row = &img[(r + dy) * ST + cb];
      float rv[16 + 2 * P];
#pragma unroll
      for (int t = 0; t < 16 + 2 * P; t++) rv[t] = row[t];
#pragma unroll
      for (int dx = 0; dx < K; dx++) {
        float wv = wsh[dy * K + dx];
#pragma unroll
        for (int o = 0; o < 16; o++) a[o] = fmaf(rv[o + dx], wv, a[o]);
      }
    }
#pragma unroll
    for (int o = 0; o < 16; o++)
      ge[o] = 0.5f * a[o] * (1.f + erff(a[o] * 0.70710678118654752f));
  }
  __syncthreads();

#pragma unroll
  for (int it = 0; it < 4; it++) {
    int idx = tid + it * 256;
    int rr = idx >> 4, q = idx & 15;
    us4 mv = ((const us4*)min_)[idx];
    float* md = &img[(rr + P) * ST + P + q * 4];
    md[0] = bf2f(mv.x); md[1] = bf2f(mv.y); md[2] = bf2f(mv.z); md[3] = bf2f(mv.w);
  }
  __syncthreads();

  float ma[16];
#pragma unroll
  for (int o = 0; o < 16; o++) ma[o] = 0.f;
#pragma unroll
  for (int dy = 0; dy < K; dy++) {
    const float* row = &img[(r + dy) * ST + cb];
    float rv[16 + 2 * P];
#pragma unroll
    for (int t = 0; t < 16 + 2 * P; t++) rv[t] = row[t];
#pragma unroll
    for (int dx = 0; dx < K; dx++) {
      float wv = wsh[K * K + dy * K + dx];
#pragma unroll
      for (int o = 0; o < 16; o++) ma[o] = fmaf(rv[o + dx], wv, ma[o]);
    }
  }
  __hip_bfloat16* gp = gated + (size_t)(bi * 512 + i) * HW_ + r * 64 + cb;
#pragma unroll
  for (int v = 0; v < 4; v++) {
    us4 t;
    t.x = f2bu(ge[v * 4 + 0] * ma[v * 4 + 0]);
    t.y = f2bu(ge[v * 4 + 1] * ma[v * 4 + 1]);
    t.z = f2bu(ge[v * 4 + 2] * ma[v * 4 + 2]);
    t.w = f2bu(ge[v * 4 + 3] * ma[v * 4 + 3]);
    *(us4*)(gp + v * 4) = t;
  }
}

// ---------------- inverse L2 norms of qd and kd rows ----------------
__global__ __launch_bounds__(256) void l2_invnorm(const float* __restrict__ qd,
                                                  const float* __restrict__ kd,
                                                  float* __restrict__ invn) {
  int row = blockIdx.x;  // 0..2047; <1024 -> qd, else kd
  const float* src = (row < 1024) ? (qd + (size_t)row * HW_)
                                  : (kd + (size_t)(row - 1024) * HW_);
  float s = 0.f;
  for (int n = threadIdx.x; n < HW_; n += 256) {
    float v = src[n];
    s = fmaf(v, v, s);
  }
#pragma unroll
  for (int o = 32; o >= 1; o >>= 1) s += __shfl_xor(s, o, 64);
  __shared__ float red[4];
  if ((threadIdx.x & 63) == 0) red[threadIdx.x >> 6] = s;
  __syncthreads();
  if (threadIdx.x == 0) {
    float t = red[0] + red[1] + red[2] + red[3];
    invn[row] = 1.f / fmaxf(sqrtf(t), 1e-12f);
  }
}

// ---------------- attention: partial scores over 256-position chunks ----------------
__global__ __launch_bounds__(256) void attn_score_part(const float* __restrict__ qd,
                                                       const float* __restrict__ kd,
                                                       float* __restrict__ part) {
  constexpr int ST = 258;  // even pad: b64-friendly, conflict-free reads
  __shared__ float qs[16 * ST];
  __shared__ float ks[16 * ST];
  int bh = blockIdx.x;   // 64
  int ch = blockIdx.y;   // 16 chunks of 256
  int bi = bh >> 3;
  int h = bh & 7;
  int tid = threadIdx.x;
  int c = tid >> 4;
  int d = tid & 15;

  const float* qrow = qd + (size_t)(bi * C_ + h * CH_) * HW_ + ch * 256;
  const float* krow = kd + (size_t)(bi * C_ + h * CH_) * HW_ + ch * 256;
#pragma unroll
  for (int it = 0; it < 4; it++) {
    int idx = tid + it * 256;  // 0..1023 -> row = idx>>6, q4 = idx&63
    int r = idx >> 6, q4 = idx & 63;
    float4 qv = ((const float4*)(qrow + (size_t)r * HW_))[q4];
    float4 kv = ((const float4*)(krow + (size_t)r * HW_))[q4];
    float* qdst = &qs[r * ST + q4 * 4];
    float* kdst = &ks[r * ST + q4 * 4];
    qdst[0] = qv.x; qdst[1] = qv.y; qdst[2] = qv.z; qdst[3] = qv.w;
    kdst[0] = kv.x; kdst[1] = kv.y; kdst[2] = kv.z; kdst[3] = kv.w;
  }
  __syncthreads();

  const float* qp = &qs[c * ST];
  const float* kp = &ks[d * ST];
  float acc = 0.f;
#pragma unroll 8
  for (int j = 0; j < 256; j++) acc = fmaf(qp[j], kp[j], acc);
  part[((size_t)bh * 16 + ch) * 256 + tid] = acc;
}

// ---------------- attention: reduce partials + softmax ----------------
__global__ __launch_bounds__(256) void attn_softmax(const float* __restrict__ part,
                                                    const float* __restrict__ invn,
                                                    const float* __restrict__ temp,
                                                    float* __restrict__ as_buf) {
  int bh = blockIdx.x;  // 64
  int bi = bh >> 3;
  int h = bh & 7;
  int tid = threadIdx.x;
  int c = tid >> 4;
  int d = tid & 15;
  float s = 0.f;
  const float* pp = part + (size_t)bh * 16 * 256 + tid;
#pragma unroll
  for (int ch = 0; ch < 16; ch++) s += pp[ch * 256];
  float S = s * invn[bi * C_ + h * CH_ + c] * invn[1024 + bi * C_ + h * CH_ + d] *
            temp[h];
  float mx = S;
#pragma unroll
  for (int o = 8; o >= 1; o >>= 1) mx = fmaxf(mx, __shfl_xor(mx, o, 16));
  float e = expf(S - mx);
  float sm = e;
#pragma unroll
  for (int o = 8; o >= 1; o >>= 1) sm += __shfl_xor(sm, o, 16);
  as_buf[(size_t)bh * 256 + tid] = e / sm;
}

// ---------------- attention: PV over 256-position chunks ----------------
__global__ __launch_bounds__(256) void attn_pv(const float* __restrict__ vd,
                                               const float* __restrict__ as_buf,
                                               float* __restrict__ osb) {
  __shared__ float as[16][17];
  int bh = blockIdx.x;  // 64
  int ch = blockIdx.y;  // 16
  int bi = bh >> 3;
  int h = bh & 7;
  int tid = threadIdx.x;
  if (tid < 256) {
    int cc = tid >> 4, dd = tid & 15;
    as[cc][dd] = as_buf[(size_t)bh * 256 + tid];
  }
  __syncthreads();

  int n = ch * 256 + tid;
  const float* vrow = vd + (size_t)(bi * C_ + h * CH_) * HW_ + n;
  float o_[16];
#pragma unroll
  for (int cc = 0; cc < 16; cc++) o_[cc] = 0.f;
#pragma unroll
  for (int dd = 0; dd < 16; dd++) {
    float vv = vrow[(size_t)dd * HW_];
#pragma unroll
    for (int cc = 0; cc < 16; cc++) o_[cc] = fmaf(as[cc][dd], vv, o_[cc]);
  }
  float* ob = osb + (size_t)(bi * C_ + h * CH_) * HW_ + n;
#pragma unroll
  for (int cc = 0; cc < 16; cc++) ob[(size_t)cc * HW_] = o_[cc];
}

extern "C" void kernel_launch(void* const* d_in, const int* in_sizes, int n_in,
                              void* d_out, int out_size, void* d_ws, size_t ws_size,
                              hipStream_t stream) {
  const float* x = (const float*)d_in[0];
  const float* ln1_w = (const float*)d_in[1];
  const float* ln1_b = (const float*)d_in[2];
  const float* temp = (const float*)d_in[3];
  const float* wq = (const float*)d_in[4];
  const float* wk = (const float*)d_in[5];
  const float* wv = (const float*)d_in[6];
  const float* dw[9];
  for (int i = 0; i < 9; i++) dw[i] = (const float*)d_in[7 + i];
  const float* attn_po = (const float*)d_in[16];
  const float* ln2_w = (const float*)d_in[17];
  const float* ln2_b = (const float*)d_in[18];
  const float* ffn_in = (const float*)d_in[19];
  const float* ffn_dw[3] = {(const float*)d_in[20], (const float*)d_in[21],
                            (const float*)d_in[22]};
  const float* ffn_po = (const float*)d_in[23];
  float* out = (float*)d_out;

  // ---- workspace layout: peak 128 MiB + 72 KiB, lifetime-aliased ----
  const size_t MB = (size_t)1 << 20;
  char* wsb = (char*)d_ws;
  float* xn = (float*)(wsb + 0 * MB);
  float* q0 = (float*)(wsb + 16 * MB);
  float* k0 = (float*)(wsb + 32 * MB);
  float* v0 = (float*)(wsb + 48 * MB);
  float* qd = (float*)(wsb + 64 * MB);
  float* kd = (float*)(wsb + 80 * MB);
  float* vd = (float*)(wsb + 96 * MB);
  float* x2 = (float*)(wsb + 112 * MB);
  float* invn = (float*)(wsb + 128 * MB);             // 8 KiB
  float* as_buf = (float*)(wsb + 128 * MB + 8 * 1024);  // 64 KiB
  float* osb = xn;
  float* xn2 = xn;
  float* part = xn;  // 4 MB partial-score buffer; dead before osb is written
  __hip_bfloat16* xin = (__hip_bfloat16*)(wsb + 16 * MB);    // 64 MB
  __hip_bfloat16* gated = (__hip_bfloat16*)(wsb + 80 * MB);  // 32 MB

  const int ln_grid = (B_ * HW_) / 256;                  // 128
  const int c128_grid = B_ * (C_ / 16) * 4;              // 256
  const int c1024_grid = B_ * (1024 / 16) * 4;           // 2048
  const dim3 dwt_grid(B_ * C_, 3);                       // 1024 x 3
  const int ffg_grid = B_ * 512;                         // 4096
  const dim3 att_grid(B_ * HEADS_, 16);                  // 64 x 16

  // ---- attention branch ----
  ln_ch<<<ln_grid, 256, 0, stream>>>(x, ln1_w, ln1_b, xn);
  conv1x1_v<C_, float, float><<<c128_grid, 256, 0, stream>>>(xn, wq, nullptr, q0, C_, C_, 0);
  conv1x1_v<C_, float, float><<<c128_grid, 256, 0, stream>>>(xn, wk, nullptr, k0, C_, C_, 0);
  conv1x1_v<C_, float, float><<<c128_grid, 256, 0, stream>>>(xn, wv, nullptr, v0, C_, C_, 0);

  for (int s = 0; s < 3; s++) {
    if (s == 0)
      dwconv_t<3><<<dwt_grid, 256, 0, stream>>>(q0, k0, v0, dw[0], dw[1], dw[2], qd, kd, vd);
    else if (s == 1)
      dwconv_t<5><<<dwt_grid, 256, 0, stream>>>(q0, k0, v0, dw[3], dw[4], dw[5], qd, kd, vd);
    else
      dwconv_t<7><<<dwt_grid, 256, 0, stream>>>(q0, k0, v0, dw[6], dw[7], dw[8], qd, kd, vd);
    l2_invnorm<<<2048, 256, 0, stream>>>(qd, kd, invn);
    attn_score_part<<<att_grid, 256, 0, stream>>>(qd, kd, part);
    attn_softmax<<<B_ * HEADS_, 256, 0, stream>>>(part, invn, temp, as_buf);
    attn_pv<<<att_grid, 256, 0, stream>>>(vd, as_buf, osb);
    conv1x1_v<C_, float, float><<<c128_grid, 256, 0, stream>>>(
        osb, attn_po + s * C_, (s == 0) ? x : nullptr, x2, C_, 3 * C_, s == 0 ? 0 : 1);
  }

  // ---- FFN branch ----
  ln_ch<<<ln_grid, 256, 0, stream>>>(x2, ln2_w, ln2_b, xn2);
  conv1x1_v<C_, float, __hip_bfloat16><<<c1024_grid, 256, 0, stream>>>(
      xn2, ffn_in, nullptr, xin, 1024, C_, 0);

  for (int s = 0; s < 3; s++) {
    if (s == 0)
      ffn_dwgate_t<3><<<ffg_grid, 256, 0, stream>>>(xin, ffn_dw[0], gated);
    else if (s == 1)
      ffn_dwgate_t<5><<<ffg_grid, 256, 0, stream>>>(xin, ffn_dw[1], gated);
    else
      ffn_dwgate_t<7><<<ffg_grid, 256, 0, stream>>>(xin, ffn_dw[2], gated);
    conv1x1_v<512, __hip_bfloat16, float><<<c128_grid, 256, 0, stream>>>(
        gated, ffn_po + s * 512, (s == 0) ? x2 : nullptr, out, C_, 3 * HID_,
        s == 0 ? 0 : 1);
  }
  (void)in_sizes; (void)n_in; (void)out_size; (void)ws_size;
}